// Round 8
// baseline (566.550 us; speedup 1.0000x reference)
//
#include <hip/hip_runtime.h>

#define NN 50000
#define NE 800000
#define NR 6
#define FD 128
#define NS (NN * NR)              // segment count (dst,rel)
#define MB ((NS + 1023) / 1024)   // scan blocks (293)

typedef __attribute__((ext_vector_type(8))) short bf16x8;
typedef __attribute__((ext_vector_type(4))) float f32x4;

__device__ __forceinline__ unsigned short f2bf(float x) {
    unsigned u = __float_as_uint(x);
    u += 0x7FFFu + ((u >> 16) & 1u);          // round-to-nearest-even
    return (unsigned short)(u >> 16);
}
__device__ __forceinline__ unsigned pack2bf(float lo, float hi) {
    return (unsigned)f2bf(lo) | ((unsigned)f2bf(hi) << 16);
}
__device__ __forceinline__ float bf_lo(unsigned u) { return __uint_as_float(u << 16); }
__device__ __forceinline__ float bf_hi(unsigned u) { return __uint_as_float(u & 0xFFFF0000u); }

// ---------------------------------------------------------------------------
// node_h f32 -> packed bf16x2
// ---------------------------------------------------------------------------
__global__ __launch_bounds__(256) void k_cast(
    const float* __restrict__ node_h, unsigned* __restrict__ nh2)
{
    int i = (blockIdx.x * 256 + threadIdx.x) * 8;   // grid sized exactly
    float4 a = *(const float4*)(node_h + i);
    float4 b = *(const float4*)(node_h + i + 4);
    uint4 o;
    o.x = pack2bf(a.x, a.y); o.y = pack2bf(a.z, a.w);
    o.z = pack2bf(b.x, b.y); o.w = pack2bf(b.z, b.w);
    *(uint4*)(nh2 + i / 2) = o;
}

// ---------------------------------------------------------------------------
// Counting sort by seg = dst*NR + rel
// ---------------------------------------------------------------------------
__global__ __launch_bounds__(256) void k_hist(
    const int* __restrict__ edst, const int* __restrict__ erel,
    int* __restrict__ cnt)
{
    int e = blockIdx.x * 256 + threadIdx.x;
    if (e < NE) atomicAdd(cnt + edst[e] * NR + erel[e], 1);
}

// Stage 1: per-block (1024 elems) sums. Coalesced int4.
__global__ __launch_bounds__(256) void k_bsum(
    const int* __restrict__ cnt, int* __restrict__ bsum)
{
    __shared__ int red[256];
    const int b = blockIdx.x, t = threadIdx.x;
    int idx0 = b * 1024 + t * 4;
    int4 c = *(const int4*)(cnt + idx0);   // cnt is padded; mask below
    int s = 0;
    if (idx0 + 0 < NS) s += c.x;
    if (idx0 + 1 < NS) s += c.y;
    if (idx0 + 2 < NS) s += c.z;
    if (idx0 + 3 < NS) s += c.w;
    red[t] = s;
    __syncthreads();
    for (int off = 128; off > 0; off >>= 1) {
        if (t < off) red[t] += red[t + off];
        __syncthreads();
    }
    if (t == 0) bsum[b] = red[0];
}

// Stage 2: one block scans the MB block sums -> exclusive prefixes.
__global__ __launch_bounds__(512) void k_scanb(
    const int* __restrict__ bsum, int* __restrict__ bpre)
{
    __shared__ int s[512];
    const int t = threadIdx.x;
    int v = (t < MB) ? bsum[t] : 0;
    s[t] = v;
    __syncthreads();
    for (int off = 1; off < 512; off <<= 1) {
        int x = (t >= off) ? s[t - off] : 0;
        __syncthreads();
        if (t >= off) s[t] += x;
        __syncthreads();
    }
    bpre[t] = s[t] - v;   // exclusive
}

// Stage 3: per-block exclusive scan + bpre, writes offs and cursor. Coalesced.
__global__ __launch_bounds__(256) void k_scan3(
    const int* __restrict__ cnt, const int* __restrict__ bpre,
    int* __restrict__ offs, int* __restrict__ cursor)
{
    __shared__ int partial[256];
    const int b = blockIdx.x, t = threadIdx.x;
    int idx0 = b * 1024 + t * 4;
    int4 c = *(const int4*)(cnt + idx0);
    if (idx0 + 0 >= NS) c.x = 0;
    if (idx0 + 1 >= NS) c.y = 0;
    if (idx0 + 2 >= NS) c.z = 0;
    if (idx0 + 3 >= NS) c.w = 0;
    int tsum = c.x + c.y + c.z + c.w;
    partial[t] = tsum;
    __syncthreads();
    for (int off = 1; off < 256; off <<= 1) {
        int x = (t >= off) ? partial[t - off] : 0;
        __syncthreads();
        if (t >= off) partial[t] += x;
        __syncthreads();
    }
    int base = bpre[b] + partial[t] - tsum;
    int4 o;
    o.x = base;
    o.y = base + c.x;
    o.z = base + c.x + c.y;
    o.w = base + c.x + c.y + c.z;
    if (idx0 + 3 < NS) {
        *(int4*)(offs + idx0) = o;
        *(int4*)(cursor + idx0) = o;
    } else {
        int v[4] = {o.x, o.y, o.z, o.w};
        for (int k = 0; k < 4; ++k)
            if (idx0 + k < NS) { offs[idx0 + k] = v[k]; cursor[idx0 + k] = v[k]; }
    }
    if (b == 0 && t == 0) offs[NS] = NE;
}

__global__ __launch_bounds__(256) void k_place(
    const int* __restrict__ esrc, const int* __restrict__ edst,
    const int* __restrict__ erel, int* __restrict__ cursor,
    int* __restrict__ eidx)
{
    int e = blockIdx.x * 256 + threadIdx.x;
    if (e >= NE) return;
    int seg = edst[e] * NR + erel[e];
    int pos = atomicAdd(cursor + seg, 1);
    eidx[pos] = esrc[e];
}

// ---------------------------------------------------------------------------
// w1[r][f] = sum_o weight[r][f][o]*att1[o]; w2 likewise with att2.
// ---------------------------------------------------------------------------
__global__ __launch_bounds__(256) void k_prep_w(
    const float* __restrict__ weight,
    const float* __restrict__ att1, const float* __restrict__ att2,
    float* __restrict__ w1, float* __restrict__ w2)
{
    __shared__ float a1s[FD], a2s[FD];
    const int r = blockIdx.x;
    const int t = threadIdx.x;
    if (t < FD) { a1s[t] = att1[t]; a2s[t] = att2[t]; }
    __syncthreads();
    int f = t & 127;
    const float* av = (t < FD) ? a1s : a2s;
    float* wo = (t < FD) ? w1 : w2;
    const float* Wrow = weight + ((size_t)r * FD + f) * FD;
    float acc = 0.f;
#pragma unroll 8
    for (int o = 0; o < FD; ++o) acc += Wrow[o] * av[o];
    wo[r * FD + f] = acc;
}

// ---------------------------------------------------------------------------
// U_h[r] = W[r] @ Wc_h^T, packed bf16 in MFMA B-fragment order.
// ---------------------------------------------------------------------------
__global__ __launch_bounds__(256) void k_prep_U(
    const float* __restrict__ weight, const float* __restrict__ Wc,
    short* __restrict__ Upk)
{
    __shared__ float As[64 * 65];
    __shared__ float Bs[64 * 132];
    const int h  = blockIdx.y / NR;
    const int r  = blockIdx.y % NR;
    const int f0 = blockIdx.x * 64;
    const int t  = threadIdx.x;
    const int tm = t & 15, tn = t >> 4;

    float acc[4][8];
#pragma unroll
    for (int i = 0; i < 4; ++i)
#pragma unroll
        for (int j = 0; j < 8; ++j) acc[i][j] = 0.f;

    for (int kt = 0; kt < 2; ++kt) {
#pragma unroll
        for (int i = 0; i < 4; ++i) {
            int flat = i * 1024 + t * 4;
            int row = flat >> 6, k = flat & 63;
            float4 v = *(const float4*)(weight + ((size_t)r * FD + f0 + row) * FD + kt * 64 + k);
            float* p = As + row * 65 + k;
            p[0] = v.x; p[1] = v.y; p[2] = v.z; p[3] = v.w;
        }
#pragma unroll
        for (int i = 0; i < 8; ++i) {
            int flat4 = i * 256 + t;
            int o = flat4 >> 4, j4 = flat4 & 15;
            float4 v = *(const float4*)(Wc + (size_t)o * 256 + h * FD + kt * 64 + j4 * 4);
            float* p = Bs + (j4 * 4) * 132 + o;
            p[0] = v.x; p[132] = v.y; p[264] = v.z; p[396] = v.w;
        }
        __syncthreads();
#pragma unroll 4
        for (int k = 0; k < 64; ++k) {
            float aa[4];
#pragma unroll
            for (int i = 0; i < 4; ++i) aa[i] = As[(4 * tm + i) * 65 + k];
            float4 blo = *(const float4*)(Bs + k * 132 + 8 * tn);
            float4 bhi = *(const float4*)(Bs + k * 132 + 8 * tn + 4);
            float bb[8] = {blo.x, blo.y, blo.z, blo.w, bhi.x, bhi.y, bhi.z, bhi.w};
#pragma unroll
            for (int i = 0; i < 4; ++i)
#pragma unroll
                for (int j = 0; j < 8; ++j) acc[i][j] += aa[i] * bb[j];
        }
        __syncthreads();
    }

#pragma unroll
    for (int i = 0; i < 4; ++i)
#pragma unroll
        for (int j = 0; j < 8; ++j) {
            int f = f0 + 4 * tm + i, o = 8 * tn + j;
            int kstep = f >> 5, g = (f >> 3) & 3, jj = f & 7;
            int nt = o >> 4, ln = g * 16 + (o & 15);
            size_t sidx = ((((size_t)(h * NR + r) * 4 + kstep) * 8 + nt) * 64 + ln) * 8 + jj;
            Upk[sidx] = (short)f2bf(acc[i][j]);
        }
}

// ---------------------------------------------------------------------------
// Aggregate v2: one wave per dst; 4 groups of 16 lanes, each group owns one
// relation segment (pass 0: r=grp, pass 1: r=4+grp). Each lane covers 8
// features (uint4 = 16B load).
// ---------------------------------------------------------------------------
__global__ __launch_bounds__(256) void k_agg(
    const unsigned* __restrict__ nh2,   // [NN][64] packed bf16x2
    const int* __restrict__ offs,       // [NS+1]
    const int* __restrict__ eidx,       // [NE] src
    const float* __restrict__ w1v, const float* __restrict__ w2v,
    unsigned* __restrict__ aggp,        // [NR][NN][64]
    float* __restrict__ s1o, float* __restrict__ s2o)
{
    const int t = threadIdx.x;
    const int lane = t & 63;
    const int grp = lane >> 4;          // relation group
    const int fl  = lane & 15;          // feature slot: features fl*8..fl*8+7
    const int d = blockIdx.x * 4 + (t >> 6);
    if (d >= NN) return;

    float p1v[2], p2v[2];

#pragma unroll
    for (int pass = 0; pass < 2; ++pass) {
        const int r = pass * 4 + grp;
        float q1 = 0.f, q2 = 0.f;
        if (r < NR) {
            const int sbeg = offs[d * NR + r];
            const int send = offs[d * NR + r + 1];
            float a0 = 0.f, a1 = 0.f, a2 = 0.f, a3 = 0.f;
            float a4 = 0.f, a5 = 0.f, a6 = 0.f, a7 = 0.f;
            for (int j = sbeg; j < send; ++j) {
                int s = eidx[j];
                uint4 v = *(const uint4*)(nh2 + (size_t)s * 64 + fl * 4);
                a0 += bf_lo(v.x); a1 += bf_hi(v.x);
                a2 += bf_lo(v.y); a3 += bf_hi(v.y);
                a4 += bf_lo(v.z); a5 += bf_hi(v.z);
                a6 += bf_lo(v.w); a7 += bf_hi(v.w);
            }
            float sc = 1.0f / (1.0f + (float)(send - sbeg));
            a0 *= sc; a1 *= sc; a2 *= sc; a3 *= sc;
            a4 *= sc; a5 *= sc; a6 *= sc; a7 *= sc;
            uint4 o;
            o.x = pack2bf(a0, a1); o.y = pack2bf(a2, a3);
            o.z = pack2bf(a4, a5); o.w = pack2bf(a6, a7);
            *(uint4*)(aggp + ((size_t)r * NN + d) * 64 + fl * 4) = o;
            float4 wa = *(const float4*)(w1v + r * FD + fl * 8);
            float4 wb = *(const float4*)(w1v + r * FD + fl * 8 + 4);
            float4 wc = *(const float4*)(w2v + r * FD + fl * 8);
            float4 wd = *(const float4*)(w2v + r * FD + fl * 8 + 4);
            q1 = a0 * wa.x + a1 * wa.y + a2 * wa.z + a3 * wa.w
               + a4 * wb.x + a5 * wb.y + a6 * wb.z + a7 * wb.w;
            q2 = a0 * wc.x + a1 * wc.y + a2 * wc.z + a3 * wc.w
               + a4 * wd.x + a5 * wd.y + a6 * wd.z + a7 * wd.w;
        }
        // in-group (16-lane) reduction
#pragma unroll
        for (int off = 1; off < 16; off <<= 1) {
            q1 += __shfl_xor(q1, off, 64);
            q2 += __shfl_xor(q2, off, 64);
        }
        p1v[pass] = q1; p2v[pass] = q2;
    }

    // broadcast the 6 logits to all lanes
    float p1[NR], p2[NR];
#pragma unroll
    for (int r = 0; r < 4; ++r) {
        p1[r] = __shfl(p1v[0], r * 16, 64);
        p2[r] = __shfl(p2v[0], r * 16, 64);
    }
    p1[4] = __shfl(p1v[1], 0, 64);  p1[5] = __shfl(p1v[1], 16, 64);
    p2[4] = __shfl(p2v[1], 0, 64);  p2[5] = __shfl(p2v[1], 16, 64);

    float m1 = p1[0], m2 = p2[0];
#pragma unroll
    for (int r = 1; r < NR; ++r) { m1 = fmaxf(m1, p1[r]); m2 = fmaxf(m2, p2[r]); }
    float e1[NR], e2[NR], d1 = 0.f, d2 = 0.f;
#pragma unroll
    for (int r = 0; r < NR; ++r) {
        e1[r] = __expf(p1[r] - m1); d1 += e1[r];
        e2[r] = __expf(p2[r] - m2); d2 += e2[r];
    }
    d1 = 1.0f / d1; d2 = 1.0f / d2;
    if (lane == 0) {
#pragma unroll
        for (int r = 0; r < NR; ++r) {
            s1o[d * NR + r] = e1[r] * d1;
            s2o[d * NR + r] = e2[r] * d2;
        }
    }
}

// ---------------------------------------------------------------------------
// Fused output GEMM v4 (bf16 MFMA, barrier-free main loop):
//   out[n] = sum_r s1[n,r]*(agg_r[n] @ U1_r) + s2[n,r]*(agg_r[n] @ U2_r) + 6*bc
// Round-8 fix: round 7 was grid-bound (782 blocks x 4 waves = 3128 waves vs
// 8192 slots -> occupancy ceiling 38%). Split columns over blockIdx.y:
// grid = 1564 blocks, wave = 32 rows x 32 cols (2 row-frags x 2 col-tiles).
// ---------------------------------------------------------------------------
__global__ __launch_bounds__(256, 4) void k_fused(
    const unsigned* __restrict__ aggp,  // [NR][NN][64] u32
    const float* __restrict__ s1, const float* __restrict__ s2,
    const short* __restrict__ Upk,
    const float* __restrict__ bc,
    float* __restrict__ out)
{
    __shared__ float sl[2 * 64 * NR];   // [h][row][r]
    const int n0 = blockIdx.x * 64;
    const int t = threadIdx.x;
    const int lane = t & 63;
    const int w = t >> 6;
    const int wrow = (w & 1) * 32;                       // wave row base (local)
    const int nt0 = blockIdx.y * 4 + (w >> 1) * 2;       // global col-tile base

    for (int i = t; i < 2 * 64 * NR; i += 256) {
        int h = i / (64 * NR);
        int rr = i % (64 * NR);
        int row = rr / NR, r = rr % NR;
        int n = n0 + row;
        float v = 0.f;
        if (n < NN) v = (h ? s2 : s1)[(size_t)n * NR + r];
        sl[i] = v;
    }
    __syncthreads();                    // only barrier in the kernel

    const int g = lane >> 4;
    const int m0 = n0 + wrow + (lane & 15);
    const unsigned* arow0 = aggp + (size_t)min(m0, NN - 1) * 64 + g * 4;
    const unsigned* arow1 = aggp + (size_t)min(m0 + 16, NN - 1) * 64 + g * 4;

    f32x4 acc[2][2];
#pragma unroll
    for (int rf = 0; rf < 2; ++rf)
#pragma unroll
        for (int nt = 0; nt < 2; ++nt) acc[rf][nt] = (f32x4){0.f, 0.f, 0.f, 0.f};

    const int rq = (lane >> 4) * 4;     // row offset within 16 from C-layout

    for (int r = 0; r < NR; ++r) {
        // A fragments for both row-frags, all 4 k-steps (reused across h)
        bf16x8 af[2][4];
#pragma unroll
        for (int kstep = 0; kstep < 4; ++kstep) {
            af[0][kstep] = *(const bf16x8*)(arow0 + (size_t)r * (NN * 64) + kstep * 16);
            af[1][kstep] = *(const bf16x8*)(arow1 + (size_t)r * (NN * 64) + kstep * 16);
        }

#pragma unroll
        for (int h = 0; h < 2; ++h) {
            f32x4 ar[2][2];
#pragma unroll
            for (int rf = 0; rf < 2; ++rf)
#pragma unroll
                for (int nt = 0; nt < 2; ++nt) ar[rf][nt] = (f32x4){0.f, 0.f, 0.f, 0.f};
            const short* Ub = Upk + ((size_t)(h * NR + r) * 4) * 8 * 512 + lane * 8;
#pragma unroll
            for (int kstep = 0; kstep < 4; ++kstep) {
#pragma unroll
                for (int nt = 0; nt < 2; ++nt) {
                    bf16x8 bfr = *(const bf16x8*)(Ub + ((size_t)kstep * 8 + nt0 + nt) * 512);
                    ar[0][nt] = __builtin_amdgcn_mfma_f32_16x16x32_bf16(af[0][kstep], bfr, ar[0][nt], 0, 0, 0);
                    ar[1][nt] = __builtin_amdgcn_mfma_f32_16x16x32_bf16(af[1][kstep], bfr, ar[1][nt], 0, 0, 0);
                }
            }
#pragma unroll
            for (int rf = 0; rf < 2; ++rf) {
                float sv[4];
#pragma unroll
                for (int reg = 0; reg < 4; ++reg)
                    sv[reg] = sl[h * 64 * NR + (wrow + rf * 16 + rq + reg) * NR + r];
#pragma unroll
                for (int nt = 0; nt < 2; ++nt)
#pragma unroll
                    for (int reg = 0; reg < 4; ++reg)
                        acc[rf][nt][reg] += sv[reg] * ar[rf][nt][reg];
            }
        }
    }

    const int colb = nt0 * 16 + (lane & 15);
#pragma unroll
    for (int rf = 0; rf < 2; ++rf) {
        int rowbase = n0 + wrow + rf * 16 + rq;
#pragma unroll
        for (int nt = 0; nt < 2; ++nt) {
            int col = colb + nt * 16;
            float b6 = 6.0f * bc[col];
#pragma unroll
            for (int reg = 0; reg < 4; ++reg) {
                int n = rowbase + reg;
                if (n < NN) out[(size_t)n * FD + col] = acc[rf][nt][reg] + b6;
            }
        }
    }
}

// ---------------------------------------------------------------------------
extern "C" void kernel_launch(void* const* d_in, const int* in_sizes, int n_in,
                              void* d_out, int out_size, void* d_ws, size_t ws_size,
                              hipStream_t stream)
{
    const float* node_h = (const float*)d_in[0];
    const float* weight = (const float*)d_in[1];
    const float* att1   = (const float*)d_in[2];
    const float* att2   = (const float*)d_in[3];
    const float* Wc     = (const float*)d_in[4];
    const float* bc     = (const float*)d_in[5];
    const int* esrc = (const int*)d_in[6];
    const int* edst = (const int*)d_in[7];
    const int* erel = (const int*)d_in[8];
    float* out = (float*)d_out;

    char* wsp = (char*)d_ws;
    auto alloc = [&](size_t bytes) {
        char* p = wsp;
        wsp += (bytes + 255) & ~(size_t)255;
        return p;
    };
    unsigned* aggp = (unsigned*)alloc((size_t)NR * NN * 64 * 4);
    unsigned* nh2  = (unsigned*)alloc((size_t)NN * 64 * 4);
    short* Upk     = (short*)alloc((size_t)2 * NR * FD * FD * 2);
    float* w1      = (float*)alloc(NR * FD * 4);
    float* w2      = (float*)alloc(NR * FD * 4);
    float* s1      = (float*)alloc((size_t)NN * NR * 4);
    float* s2      = (float*)alloc((size_t)NN * NR * 4);
    int* offs      = (int*)alloc((size_t)(NS + 1 + 64) * 4);
    int* cursor    = (int*)alloc((size_t)(NS + 2048) * 4);  // also 'cnt'; padded for int4 tails
    int* bsum      = (int*)alloc(512 * 4);
    int* bpre      = (int*)alloc(512 * 4);
    int* eidx      = (int*)d_out;   // scratch in out's h-region; consumed by k_agg

    hipMemsetAsync(cursor, 0, (size_t)NS * sizeof(int), stream);

    k_hist<<<(NE + 255) / 256, 256, 0, stream>>>(edst, erel, cursor);
    k_bsum<<<MB, 256, 0, stream>>>(cursor, bsum);
    k_scanb<<<1, 512, 0, stream>>>(bsum, bpre);
    k_scan3<<<MB, 256, 0, stream>>>(cursor, bpre, offs, cursor);
    k_place<<<(NE + 255) / 256, 256, 0, stream>>>(esrc, edst, erel, cursor, eidx);

    k_cast<<<(NN * FD / 8 + 255) / 256, 256, 0, stream>>>(node_h, nh2);
    k_prep_w<<<NR, 256, 0, stream>>>(weight, att1, att2, w1, w2);
    k_prep_U<<<dim3(2, 2 * NR), 256, 0, stream>>>(weight, Wc, Upk);

    k_agg<<<(NN + 3) / 4, 256, 0, stream>>>(nh2, offs, eidx, w1, w2, aggp, s1, s2);

    dim3 gf((NN + 63) / 64, 2);
    k_fused<<<gf, 256, 0, stream>>>(aggp, s1, s2, Upk, bc, out);

    hipMemcpyAsync(out + (size_t)NN * FD, weight,
                   (size_t)NR * FD * FD * sizeof(float),
                   hipMemcpyDeviceToDevice, stream);
}

// Round 9
// 552.999 us; speedup vs baseline: 1.0245x; 1.0245x over previous
//
#include <hip/hip_runtime.h>

#define NN 50000
#define NE 800000
#define NR 6
#define FD 128
#define NS (NN * NR)              // segment count (dst,rel)
#define MB ((NS + 1023) / 1024)   // scan blocks (293)

typedef __attribute__((ext_vector_type(8))) short bf16x8;
typedef __attribute__((ext_vector_type(4))) float f32x4;

__device__ __forceinline__ unsigned short f2bf(float x) {
    unsigned u = __float_as_uint(x);
    u += 0x7FFFu + ((u >> 16) & 1u);          // round-to-nearest-even
    return (unsigned short)(u >> 16);
}
__device__ __forceinline__ unsigned pack2bf(float lo, float hi) {
    return (unsigned)f2bf(lo) | ((unsigned)f2bf(hi) << 16);
}
__device__ __forceinline__ float bf_lo(unsigned u) { return __uint_as_float(u << 16); }
__device__ __forceinline__ float bf_hi(unsigned u) { return __uint_as_float(u & 0xFFFF0000u); }

// ---------------------------------------------------------------------------
// node_h f32 -> packed bf16x2
// ---------------------------------------------------------------------------
__global__ __launch_bounds__(256) void k_cast(
    const float* __restrict__ node_h, unsigned* __restrict__ nh2)
{
    int i = (blockIdx.x * 256 + threadIdx.x) * 8;   // grid sized exactly
    float4 a = *(const float4*)(node_h + i);
    float4 b = *(const float4*)(node_h + i + 4);
    uint4 o;
    o.x = pack2bf(a.x, a.y); o.y = pack2bf(a.z, a.w);
    o.z = pack2bf(b.x, b.y); o.w = pack2bf(b.z, b.w);
    *(uint4*)(nh2 + i / 2) = o;
}

// ---------------------------------------------------------------------------
// Counting sort by seg = dst*NR + rel
// ---------------------------------------------------------------------------
__global__ __launch_bounds__(256) void k_hist(
    const int* __restrict__ edst, const int* __restrict__ erel,
    int* __restrict__ cnt)
{
    int e = blockIdx.x * 256 + threadIdx.x;
    if (e < NE) atomicAdd(cnt + edst[e] * NR + erel[e], 1);
}

// Stage 1: per-block (1024 elems) sums. Coalesced int4.
__global__ __launch_bounds__(256) void k_bsum(
    const int* __restrict__ cnt, int* __restrict__ bsum)
{
    __shared__ int red[256];
    const int b = blockIdx.x, t = threadIdx.x;
    int idx0 = b * 1024 + t * 4;
    int4 c = *(const int4*)(cnt + idx0);   // cnt is padded; mask below
    int s = 0;
    if (idx0 + 0 < NS) s += c.x;
    if (idx0 + 1 < NS) s += c.y;
    if (idx0 + 2 < NS) s += c.z;
    if (idx0 + 3 < NS) s += c.w;
    red[t] = s;
    __syncthreads();
    for (int off = 128; off > 0; off >>= 1) {
        if (t < off) red[t] += red[t + off];
        __syncthreads();
    }
    if (t == 0) bsum[b] = red[0];
}

// Stage 2: one block scans the MB block sums -> exclusive prefixes.
__global__ __launch_bounds__(512) void k_scanb(
    const int* __restrict__ bsum, int* __restrict__ bpre)
{
    __shared__ int s[512];
    const int t = threadIdx.x;
    int v = (t < MB) ? bsum[t] : 0;
    s[t] = v;
    __syncthreads();
    for (int off = 1; off < 512; off <<= 1) {
        int x = (t >= off) ? s[t - off] : 0;
        __syncthreads();
        if (t >= off) s[t] += x;
        __syncthreads();
    }
    bpre[t] = s[t] - v;   // exclusive
}

// Stage 3: per-block exclusive scan + bpre, writes offs and cursor. Coalesced.
__global__ __launch_bounds__(256) void k_scan3(
    const int* __restrict__ cnt, const int* __restrict__ bpre,
    int* __restrict__ offs, int* __restrict__ cursor)
{
    __shared__ int partial[256];
    const int b = blockIdx.x, t = threadIdx.x;
    int idx0 = b * 1024 + t * 4;
    int4 c = *(const int4*)(cnt + idx0);
    if (idx0 + 0 >= NS) c.x = 0;
    if (idx0 + 1 >= NS) c.y = 0;
    if (idx0 + 2 >= NS) c.z = 0;
    if (idx0 + 3 >= NS) c.w = 0;
    int tsum = c.x + c.y + c.z + c.w;
    partial[t] = tsum;
    __syncthreads();
    for (int off = 1; off < 256; off <<= 1) {
        int x = (t >= off) ? partial[t - off] : 0;
        __syncthreads();
        if (t >= off) partial[t] += x;
        __syncthreads();
    }
    int base = bpre[b] + partial[t] - tsum;
    int4 o;
    o.x = base;
    o.y = base + c.x;
    o.z = base + c.x + c.y;
    o.w = base + c.x + c.y + c.z;
    if (idx0 + 3 < NS) {
        *(int4*)(offs + idx0) = o;
        *(int4*)(cursor + idx0) = o;
    } else {
        int v[4] = {o.x, o.y, o.z, o.w};
        for (int k = 0; k < 4; ++k)
            if (idx0 + k < NS) { offs[idx0 + k] = v[k]; cursor[idx0 + k] = v[k]; }
    }
    if (b == 0 && t == 0) offs[NS] = NE;
}

__global__ __launch_bounds__(256) void k_place(
    const int* __restrict__ esrc, const int* __restrict__ edst,
    const int* __restrict__ erel, int* __restrict__ cursor,
    int* __restrict__ eidx)
{
    int e = blockIdx.x * 256 + threadIdx.x;
    if (e >= NE) return;
    int seg = edst[e] * NR + erel[e];
    int pos = atomicAdd(cursor + seg, 1);
    eidx[pos] = esrc[e];
}

// ---------------------------------------------------------------------------
// w1[r][f] = sum_o weight[r][f][o]*att1[o]; w2 likewise with att2.
// ---------------------------------------------------------------------------
__global__ __launch_bounds__(256) void k_prep_w(
    const float* __restrict__ weight,
    const float* __restrict__ att1, const float* __restrict__ att2,
    float* __restrict__ w1, float* __restrict__ w2)
{
    __shared__ float a1s[FD], a2s[FD];
    const int r = blockIdx.x;
    const int t = threadIdx.x;
    if (t < FD) { a1s[t] = att1[t]; a2s[t] = att2[t]; }
    __syncthreads();
    int f = t & 127;
    const float* av = (t < FD) ? a1s : a2s;
    float* wo = (t < FD) ? w1 : w2;
    const float* Wrow = weight + ((size_t)r * FD + f) * FD;
    float acc = 0.f;
#pragma unroll 8
    for (int o = 0; o < FD; ++o) acc += Wrow[o] * av[o];
    wo[r * FD + f] = acc;
}

// ---------------------------------------------------------------------------
// U_h[r] = W[r] @ Wc_h^T, packed bf16 in MFMA B-fragment order.
// ---------------------------------------------------------------------------
__global__ __launch_bounds__(256) void k_prep_U(
    const float* __restrict__ weight, const float* __restrict__ Wc,
    short* __restrict__ Upk)
{
    __shared__ float As[64 * 65];
    __shared__ float Bs[64 * 132];
    const int h  = blockIdx.y / NR;
    const int r  = blockIdx.y % NR;
    const int f0 = blockIdx.x * 64;
    const int t  = threadIdx.x;
    const int tm = t & 15, tn = t >> 4;

    float acc[4][8];
#pragma unroll
    for (int i = 0; i < 4; ++i)
#pragma unroll
        for (int j = 0; j < 8; ++j) acc[i][j] = 0.f;

    for (int kt = 0; kt < 2; ++kt) {
#pragma unroll
        for (int i = 0; i < 4; ++i) {
            int flat = i * 1024 + t * 4;
            int row = flat >> 6, k = flat & 63;
            float4 v = *(const float4*)(weight + ((size_t)r * FD + f0 + row) * FD + kt * 64 + k);
            float* p = As + row * 65 + k;
            p[0] = v.x; p[1] = v.y; p[2] = v.z; p[3] = v.w;
        }
#pragma unroll
        for (int i = 0; i < 8; ++i) {
            int flat4 = i * 256 + t;
            int o = flat4 >> 4, j4 = flat4 & 15;
            float4 v = *(const float4*)(Wc + (size_t)o * 256 + h * FD + kt * 64 + j4 * 4);
            float* p = Bs + (j4 * 4) * 132 + o;
            p[0] = v.x; p[132] = v.y; p[264] = v.z; p[396] = v.w;
        }
        __syncthreads();
#pragma unroll 4
        for (int k = 0; k < 64; ++k) {
            float aa[4];
#pragma unroll
            for (int i = 0; i < 4; ++i) aa[i] = As[(4 * tm + i) * 65 + k];
            float4 blo = *(const float4*)(Bs + k * 132 + 8 * tn);
            float4 bhi = *(const float4*)(Bs + k * 132 + 8 * tn + 4);
            float bb[8] = {blo.x, blo.y, blo.z, blo.w, bhi.x, bhi.y, bhi.z, bhi.w};
#pragma unroll
            for (int i = 0; i < 4; ++i)
#pragma unroll
                for (int j = 0; j < 8; ++j) acc[i][j] += aa[i] * bb[j];
        }
        __syncthreads();
    }

#pragma unroll
    for (int i = 0; i < 4; ++i)
#pragma unroll
        for (int j = 0; j < 8; ++j) {
            int f = f0 + 4 * tm + i, o = 8 * tn + j;
            int kstep = f >> 5, g = (f >> 3) & 3, jj = f & 7;
            int nt = o >> 4, ln = g * 16 + (o & 15);
            size_t sidx = ((((size_t)(h * NR + r) * 4 + kstep) * 8 + nt) * 64 + ln) * 8 + jj;
            Upk[sidx] = (short)f2bf(acc[i][j]);
        }
}

// ---------------------------------------------------------------------------
// Aggregate v2: one wave per dst; 4 groups of 16 lanes, each group owns one
// relation segment (pass 0: r=grp, pass 1: r=4+grp). Each lane covers 8
// features (uint4 = 16B load).
// ---------------------------------------------------------------------------
__global__ __launch_bounds__(256) void k_agg(
    const unsigned* __restrict__ nh2,   // [NN][64] packed bf16x2
    const int* __restrict__ offs,       // [NS+1]
    const int* __restrict__ eidx,       // [NE] src
    const float* __restrict__ w1v, const float* __restrict__ w2v,
    unsigned* __restrict__ aggp,        // [NR][NN][64]
    float* __restrict__ s1o, float* __restrict__ s2o)
{
    const int t = threadIdx.x;
    const int lane = t & 63;
    const int grp = lane >> 4;          // relation group
    const int fl  = lane & 15;          // feature slot: features fl*8..fl*8+7
    const int d = blockIdx.x * 4 + (t >> 6);
    if (d >= NN) return;

    float p1v[2], p2v[2];

#pragma unroll
    for (int pass = 0; pass < 2; ++pass) {
        const int r = pass * 4 + grp;
        float q1 = 0.f, q2 = 0.f;
        if (r < NR) {
            const int sbeg = offs[d * NR + r];
            const int send = offs[d * NR + r + 1];
            float a0 = 0.f, a1 = 0.f, a2 = 0.f, a3 = 0.f;
            float a4 = 0.f, a5 = 0.f, a6 = 0.f, a7 = 0.f;
            for (int j = sbeg; j < send; ++j) {
                int s = eidx[j];
                uint4 v = *(const uint4*)(nh2 + (size_t)s * 64 + fl * 4);
                a0 += bf_lo(v.x); a1 += bf_hi(v.x);
                a2 += bf_lo(v.y); a3 += bf_hi(v.y);
                a4 += bf_lo(v.z); a5 += bf_hi(v.z);
                a6 += bf_lo(v.w); a7 += bf_hi(v.w);
            }
            float sc = 1.0f / (1.0f + (float)(send - sbeg));
            a0 *= sc; a1 *= sc; a2 *= sc; a3 *= sc;
            a4 *= sc; a5 *= sc; a6 *= sc; a7 *= sc;
            uint4 o;
            o.x = pack2bf(a0, a1); o.y = pack2bf(a2, a3);
            o.z = pack2bf(a4, a5); o.w = pack2bf(a6, a7);
            *(uint4*)(aggp + ((size_t)r * NN + d) * 64 + fl * 4) = o;
            float4 wa = *(const float4*)(w1v + r * FD + fl * 8);
            float4 wb = *(const float4*)(w1v + r * FD + fl * 8 + 4);
            float4 wc = *(const float4*)(w2v + r * FD + fl * 8);
            float4 wd = *(const float4*)(w2v + r * FD + fl * 8 + 4);
            q1 = a0 * wa.x + a1 * wa.y + a2 * wa.z + a3 * wa.w
               + a4 * wb.x + a5 * wb.y + a6 * wb.z + a7 * wb.w;
            q2 = a0 * wc.x + a1 * wc.y + a2 * wc.z + a3 * wc.w
               + a4 * wd.x + a5 * wd.y + a6 * wd.z + a7 * wd.w;
        }
        // in-group (16-lane) reduction
#pragma unroll
        for (int off = 1; off < 16; off <<= 1) {
            q1 += __shfl_xor(q1, off, 64);
            q2 += __shfl_xor(q2, off, 64);
        }
        p1v[pass] = q1; p2v[pass] = q2;
    }

    // broadcast the 6 logits to all lanes
    float p1[NR], p2[NR];
#pragma unroll
    for (int r = 0; r < 4; ++r) {
        p1[r] = __shfl(p1v[0], r * 16, 64);
        p2[r] = __shfl(p2v[0], r * 16, 64);
    }
    p1[4] = __shfl(p1v[1], 0, 64);  p1[5] = __shfl(p1v[1], 16, 64);
    p2[4] = __shfl(p2v[1], 0, 64);  p2[5] = __shfl(p2v[1], 16, 64);

    float m1 = p1[0], m2 = p2[0];
#pragma unroll
    for (int r = 1; r < NR; ++r) { m1 = fmaxf(m1, p1[r]); m2 = fmaxf(m2, p2[r]); }
    float e1[NR], e2[NR], d1 = 0.f, d2 = 0.f;
#pragma unroll
    for (int r = 0; r < NR; ++r) {
        e1[r] = __expf(p1[r] - m1); d1 += e1[r];
        e2[r] = __expf(p2[r] - m2); d2 += e2[r];
    }
    d1 = 1.0f / d1; d2 = 1.0f / d2;
    if (lane == 0) {
#pragma unroll
        for (int r = 0; r < NR; ++r) {
            s1o[d * NR + r] = e1[r] * d1;
            s2o[d * NR + r] = e2[r] * d2;
        }
    }
}

// ---------------------------------------------------------------------------
// Fused output GEMM v5 (bf16 MFMA, barrier-free main loop, ROW-split grid):
//   out[n] = sum_r s1[n,r]*(agg_r[n] @ U1_r) + s2[n,r]*(agg_r[n] @ U2_r) + 6*bc
// Round-9 fix: round 8's COLUMN-split duplicated the 77-MB A operand across
// temporally-distant blocks -> L3 churn -> 440 MB HBM fetch. Row-split keeps
// each aggp row in exactly ONE block (A-dup only within-block, L1-served) and
// still doubles wave count vs round 7: block = 32 rows x 128 cols, 4 waves,
// wave = 32 rows x 32 cols (nt0 = w*2), grid 1563 -> 6252 waves (76% slots).
// ---------------------------------------------------------------------------
__global__ __launch_bounds__(256, 4) void k_fused(
    const unsigned* __restrict__ aggp,  // [NR][NN][64] u32
    const float* __restrict__ s1, const float* __restrict__ s2,
    const short* __restrict__ Upk,
    const float* __restrict__ bc,
    float* __restrict__ out)
{
    __shared__ float sl[2 * 32 * NR];   // [h][row][r]
    const int n0 = blockIdx.x * 32;
    const int t = threadIdx.x;
    const int lane = t & 63;
    const int w = t >> 6;
    const int nt0 = w * 2;              // wave's col-tile base (2 tiles of 16)

    for (int i = t; i < 2 * 32 * NR; i += 256) {
        int h = i / (32 * NR);
        int rr = i % (32 * NR);
        int row = rr / NR, r = rr % NR;
        int n = n0 + row;
        float v = 0.f;
        if (n < NN) v = (h ? s2 : s1)[(size_t)n * NR + r];
        sl[i] = v;
    }
    __syncthreads();                    // only barrier in the kernel

    const int g = lane >> 4;
    const int m0 = n0 + (lane & 15);
    const unsigned* arow0 = aggp + (size_t)min(m0, NN - 1) * 64 + g * 4;
    const unsigned* arow1 = aggp + (size_t)min(m0 + 16, NN - 1) * 64 + g * 4;

    f32x4 acc[2][2];
#pragma unroll
    for (int rf = 0; rf < 2; ++rf)
#pragma unroll
        for (int nt = 0; nt < 2; ++nt) acc[rf][nt] = (f32x4){0.f, 0.f, 0.f, 0.f};

    const int rq = (lane >> 4) * 4;     // row offset within 16 from C-layout

    for (int r = 0; r < NR; ++r) {
        // A fragments for both row-frags, all 4 k-steps (reused across h)
        bf16x8 af[2][4];
#pragma unroll
        for (int kstep = 0; kstep < 4; ++kstep) {
            af[0][kstep] = *(const bf16x8*)(arow0 + (size_t)r * (NN * 64) + kstep * 16);
            af[1][kstep] = *(const bf16x8*)(arow1 + (size_t)r * (NN * 64) + kstep * 16);
        }

#pragma unroll
        for (int h = 0; h < 2; ++h) {
            f32x4 ar[2][2];
#pragma unroll
            for (int rf = 0; rf < 2; ++rf)
#pragma unroll
                for (int nt = 0; nt < 2; ++nt) ar[rf][nt] = (f32x4){0.f, 0.f, 0.f, 0.f};
            const short* Ub = Upk + ((size_t)(h * NR + r) * 4) * 8 * 512 + lane * 8;
#pragma unroll
            for (int kstep = 0; kstep < 4; ++kstep) {
#pragma unroll
                for (int nt = 0; nt < 2; ++nt) {
                    bf16x8 bfr = *(const bf16x8*)(Ub + ((size_t)kstep * 8 + nt0 + nt) * 512);
                    ar[0][nt] = __builtin_amdgcn_mfma_f32_16x16x32_bf16(af[0][kstep], bfr, ar[0][nt], 0, 0, 0);
                    ar[1][nt] = __builtin_amdgcn_mfma_f32_16x16x32_bf16(af[1][kstep], bfr, ar[1][nt], 0, 0, 0);
                }
            }
#pragma unroll
            for (int rf = 0; rf < 2; ++rf) {
                float sv[4];
#pragma unroll
                for (int reg = 0; reg < 4; ++reg)
                    sv[reg] = sl[h * 32 * NR + (rf * 16 + rq + reg) * NR + r];
#pragma unroll
                for (int nt = 0; nt < 2; ++nt)
#pragma unroll
                    for (int reg = 0; reg < 4; ++reg)
                        acc[rf][nt][reg] += sv[reg] * ar[rf][nt][reg];
            }
        }
    }

    const int colb = nt0 * 16 + (lane & 15);
#pragma unroll
    for (int rf = 0; rf < 2; ++rf) {
        int rowbase = n0 + rf * 16 + rq;
#pragma unroll
        for (int nt = 0; nt < 2; ++nt) {
            int col = colb + nt * 16;
            float b6 = 6.0f * bc[col];
#pragma unroll
            for (int reg = 0; reg < 4; ++reg) {
                int n = rowbase + reg;
                if (n < NN) out[(size_t)n * FD + col] = acc[rf][nt][reg] + b6;
            }
        }
    }
}

// ---------------------------------------------------------------------------
extern "C" void kernel_launch(void* const* d_in, const int* in_sizes, int n_in,
                              void* d_out, int out_size, void* d_ws, size_t ws_size,
                              hipStream_t stream)
{
    const float* node_h = (const float*)d_in[0];
    const float* weight = (const float*)d_in[1];
    const float* att1   = (const float*)d_in[2];
    const float* att2   = (const float*)d_in[3];
    const float* Wc     = (const float*)d_in[4];
    const float* bc     = (const float*)d_in[5];
    const int* esrc = (const int*)d_in[6];
    const int* edst = (const int*)d_in[7];
    const int* erel = (const int*)d_in[8];
    float* out = (float*)d_out;

    char* wsp = (char*)d_ws;
    auto alloc = [&](size_t bytes) {
        char* p = wsp;
        wsp += (bytes + 255) & ~(size_t)255;
        return p;
    };
    unsigned* aggp = (unsigned*)alloc((size_t)NR * NN * 64 * 4);
    unsigned* nh2  = (unsigned*)alloc((size_t)NN * 64 * 4);
    short* Upk     = (short*)alloc((size_t)2 * NR * FD * FD * 2);
    float* w1      = (float*)alloc(NR * FD * 4);
    float* w2      = (float*)alloc(NR * FD * 4);
    float* s1      = (float*)alloc((size_t)NN * NR * 4);
    float* s2      = (float*)alloc((size_t)NN * NR * 4);
    int* offs      = (int*)alloc((size_t)(NS + 1 + 64) * 4);
    int* cursor    = (int*)alloc((size_t)(NS + 2048) * 4);  // also 'cnt'; padded for int4 tails
    int* bsum      = (int*)alloc(512 * 4);
    int* bpre      = (int*)alloc(512 * 4);
    int* eidx      = (int*)d_out;   // scratch in out's h-region; consumed by k_agg

    hipMemsetAsync(cursor, 0, (size_t)NS * sizeof(int), stream);

    k_hist<<<(NE + 255) / 256, 256, 0, stream>>>(edst, erel, cursor);
    k_bsum<<<MB, 256, 0, stream>>>(cursor, bsum);
    k_scanb<<<1, 512, 0, stream>>>(bsum, bpre);
    k_scan3<<<MB, 256, 0, stream>>>(cursor, bpre, offs, cursor);
    k_place<<<(NE + 255) / 256, 256, 0, stream>>>(esrc, edst, erel, cursor, eidx);

    k_cast<<<(NN * FD / 8 + 255) / 256, 256, 0, stream>>>(node_h, nh2);
    k_prep_w<<<NR, 256, 0, stream>>>(weight, att1, att2, w1, w2);
    k_prep_U<<<dim3(2, 2 * NR), 256, 0, stream>>>(weight, Wc, Upk);

    k_agg<<<(NN + 3) / 4, 256, 0, stream>>>(nh2, offs, eidx, w1, w2, aggp, s1, s2);

    k_fused<<<(NN + 31) / 32, 256, 0, stream>>>(aggp, s1, s2, Upk, bc, out);

    hipMemcpyAsync(out + (size_t)NN * FD, weight,
                   (size_t)NR * FD * FD * sizeof(float),
                   hipMemcpyDeviceToDevice, stream);
}